// Round 10
// baseline (69.213 us; speedup 1.0000x reference)
//
#include <hip/hip_runtime.h>
#include <hip/hip_bf16.h>

#define NN 16384
#define DD 64
#define NBI 32                 // 512-row bands
#define NUNITS 2112            // sum_I (128 - 4I), I=0..31
#define NBLK 768               // 3 blocks/CU (48 KB LDS each)
#define NPOSB (NN/4)
#define NH2W 512               // pass-2 waves (512*64 = 32768 hit cells)
#define SCREEN_T 0.49f         // hinge>0 needs gram > ~0.5-3e-5; margin 1e-2

constexpr float F_EPS_PD   = 1e-6f;
constexpr float F_EPS_NORM = 1e-6f;

using bf16x8 = __attribute__((ext_vector_type(8))) short;
using f32x4  = __attribute__((ext_vector_type(4))) float;
typedef __attribute__((address_space(1))) const unsigned int gu32_t;
typedef __attribute__((address_space(3))) unsigned int       lu32_t;

__device__ __forceinline__ float wave_sum_f(float v) {
    #pragma unroll
    for (int o = 32; o >= 1; o >>= 1) v += __shfl_xor(v, o);
    return v;
}

// unit offset of band I (units are (band, col-tile) with tj in [4I,128))
__device__ __forceinline__ int band_off(int I) { return 2 * I * (65 - I); }

// ---------------------------------------------------------------------------
// Kernel 1: per-row normalize + bf16 copy + packed {u,lab}/{vc,lab} + exact
// fp32 positive-pair loss.   d2(i,j) = u_i + vc_j - 2*gram(i,j)
// ---------------------------------------------------------------------------
__global__ __launch_bounds__(256) void norm_kernel(
    const float* __restrict__ emb, const int* __restrict__ pidx,
    const int* __restrict__ lab, float2* __restrict__ up,
    float2* __restrict__ vcp, __hip_bfloat16* __restrict__ ebf,
    float* __restrict__ posP) {
    int w    = threadIdx.x >> 6;
    int row  = blockIdx.x * 4 + w;
    int lane = threadIdx.x & 63;
    int j    = pidx[row];
    float x  = emb[(size_t)row * DD + lane];
    float xj = emb[(size_t)j   * DD + lane];

    float n2  = wave_sum_f(x * x);
    float sx  = wave_sum_f(x);
    float n2j = wave_sum_f(xj * xj);
    float sxj = wave_sum_f(xj);
    float dot = wave_sum_f(x * xj);

    float m  = fmaxf(sqrtf(n2),  F_EPS_NORM);
    float mj = fmaxf(sqrtf(n2j), F_EPS_NORM);
    ebf[(size_t)row * DD + lane] = __float2bfloat16(x / m);

    __shared__ float spos[4];
    if (lane == 0) {
        float sq  = n2 / (m * m);
        float sqj = n2j / (mj * mj);
        float s   = sx / m;
        float sj  = sxj / mj;
        float g   = dot / (m * mj);
        float lf  = (float)lab[row];
        up[row]  = make_float2(sq + 2.0f * F_EPS_PD * s, lf);
        vcp[row] = make_float2(
            sq - 2.0f * F_EPS_PD * s + (float)DD * F_EPS_PD * F_EPS_PD, lf);
        float d2p = sq + sqj - 2.0f * g + 2.0f * F_EPS_PD * (s - sj)
                  + (float)DD * F_EPS_PD * F_EPS_PD;
        spos[w] = fmaxf(d2p, 0.0f);
    }
    __syncthreads();
    if (threadIdx.x == 0)
        posP[blockIdx.x] = spos[0] + spos[1] + spos[2] + spos[3];
}

// ---------------------------------------------------------------------------
// Stage one B tile (16 KB) into a ring slot: exactly 2 ops per wave.
// Source XOR-preswizzled (both-sides rule): LDS row r, 16B slot c holds
// global chunk c^(r&7); matching read-XOR applied in compute.
// ---------------------------------------------------------------------------
__device__ __forceinline__ void stage_tile(const short* ebf, int tile,
                                           short* slotB, int w, int lane) {
    const short* tbase = ebf + (size_t)tile * (128 * DD);
    int rlo = lane >> 3;
    int g   = (lane & 7) ^ rlo;
    #pragma unroll
    for (int q = 0; q < 2; ++q) {
        int m = w * 2 + q;
        __builtin_amdgcn_global_load_lds(
            (gu32_t*)(const void*)(tbase + (size_t)(8 * m + rlo) * DD + g * 8),
            (lu32_t*)(void*)(slotB + m * 512), 16, 0, 0);
    }
}

// ---------------------------------------------------------------------------
// Kernel 2 (pass A, ABLATION): pure screen-GEMM. R8 skeleton (counted-vmcnt
// 3-slot ring, 2-deep prefetch) but the loop body is ONLY:
//   2 ds_read_b128 -> 8 MFMA -> fmax tree -> mask bit
// plus ONE unconditional 1-byte hitmask store per (wave,tile) — no atomics,
// no u/vc/lab staging, no sqrt, no hinge chain. Uniform vmem ops/iter
// (2 stage + 1 store) -> exact counts: vmcnt(2) first iter, vmcnt(3) steady,
// vmcnt(0) last. Exact epilogue deferred to hit_kernel.
// ---------------------------------------------------------------------------
__global__ __launch_bounds__(512, 6) void gram_kernel(
    const short* __restrict__ ebf, unsigned char* __restrict__ hitb) {
    __shared__ short ringB[3][8192];   // 3 x 16 KB B tiles (swizzled)
    int tid  = threadIdx.x;
    int w    = tid >> 6;
    int lane = tid & 63;
    int lrow = lane & 15, lkh = lane >> 4;
    int c0s  = ((lkh)     ^ (lrow & 7)) * 8;   // swizzled K[0:32) chunk
    int c1s  = ((lkh + 4) ^ (lrow & 7)) * 8;   // swizzled K[32:64) chunk

    int ks = (int)(((long long)blockIdx.x * NUNITS) / NBLK);
    int ke = (int)(((long long)(blockIdx.x + 1) * NUNITS) / NBLK);

    // decode ks -> band I
    int I = (int)((65.0f - sqrtf(4225.0f - 2.0f * (float)ks)) * 0.5f);
    I = I < 0 ? 0 : (I > NBI - 1 ? NBI - 1 : I);
    while (band_off(I) > ks) --I;
    while (I < NBI - 1 && band_off(I + 1) <= ks) ++I;

    int u0 = ks;
    while (u0 < ke) {
        int bend = band_off(I + 1);
        int n    = (ke < bend ? ke : bend) - u0;
        int tj0  = 4 * I + (u0 - band_off(I));
        int rowbase = I * 512 + w * 64;
        int strip64 = I * 8 + w;       // 64-row strip id in [0,256)
        int rt      = strip64 >> 1;    // own 128-row tile id

        // --- segment prologue: A frags + prime 2 tiles ---
        bf16x8 a[4][2];
        #pragma unroll
        for (int s = 0; s < 4; ++s) {
            const short* ab = ebf + (size_t)(rowbase + 16 * s + lrow) * DD + lkh * 8;
            a[s][0] = *(const bf16x8*)(ab);
            a[s][1] = *(const bf16x8*)(ab + 32);
        }
        stage_tile(ebf, tj0, &ringB[0][0], w, lane);
        if (n > 1) stage_tile(ebf, tj0 + 1, &ringB[1][0], w, lane);

        int sl = 0;                    // ring slot of tile k
        for (int k = 0; k < n; ++k) {
            if (k == n - 1)      asm volatile("s_waitcnt vmcnt(0)" ::: "memory");
            else if (k == 0)     asm volatile("s_waitcnt vmcnt(2)" ::: "memory");
            else                 asm volatile("s_waitcnt vmcnt(3)" ::: "memory");
            __builtin_amdgcn_s_barrier();
            __builtin_amdgcn_sched_barrier(0);
            int sl2 = (sl >= 1) ? sl - 1 : 2;     // slot of tile k+2
            if (k + 2 < n)
                stage_tile(ebf, tj0 + k + 2, &ringB[sl2][0], w, lane);

            int tj = tj0 + k;
            unsigned int mask = 0;
            if (tj >= rt) {                       // wave-uniform
                const short* lb = &ringB[sl][0];
                #pragma unroll
                for (int t = 0; t < 8; ++t) {
                    const short* rowp = lb + (t * 16 + lrow) * 64;
                    bf16x8 b0 = *(const bf16x8*)(rowp + c0s);
                    bf16x8 b1 = *(const bf16x8*)(rowp + c1s);
                    __builtin_amdgcn_s_setprio(1);
                    f32x4 c4[4];
                    #pragma unroll
                    for (int s = 0; s < 4; ++s) {
                        f32x4 z = {0.f, 0.f, 0.f, 0.f};
                        z = __builtin_amdgcn_mfma_f32_16x16x32_bf16(a[s][0], b0, z, 0, 0, 0);
                        z = __builtin_amdgcn_mfma_f32_16x16x32_bf16(a[s][1], b1, z, 0, 0, 0);
                        c4[s] = z;
                    }
                    __builtin_amdgcn_s_setprio(0);
                    float mx = fmaxf(fmaxf(c4[0][0], c4[0][1]), fmaxf(c4[0][2], c4[0][3]));
                    mx = fmaxf(mx, fmaxf(fmaxf(c4[1][0], c4[1][1]), fmaxf(c4[1][2], c4[1][3])));
                    mx = fmaxf(mx, fmaxf(fmaxf(c4[2][0], c4[2][1]), fmaxf(c4[2][2], c4[2][3])));
                    mx = fmaxf(mx, fmaxf(fmaxf(c4[3][0], c4[3][1]), fmaxf(c4[3][2], c4[3][3])));
                    if (__any(mx > SCREEN_T)) mask |= (1u << t);
                }
            }
            // unconditional store keeps vmem count uniform AND data fresh
            if (lane == 0) hitb[strip64 * 128 + tj] = (unsigned char)mask;
            sl = (sl + 1 == 3) ? 0 : sl + 1;
        }
        __builtin_amdgcn_s_barrier();  // protect ring reuse across segments
        __builtin_amdgcn_sched_barrier(0);
        u0 += n;
        ++I;
    }
}

// ---------------------------------------------------------------------------
// Kernel 3 (pass B): exact epilogue on flagged sub-tiles only (~5K of 132K).
// 512 waves; wave gw scans its 64 bytes (coalesced) + ballot; per flagged
// (strip64, tj) re-runs the identical MFMA (bit-identical values: same bf16
// inputs, same accumulate order) + exact d2/hinge/label math (R8-verified
// formulas). Lower-triangle cells (never written, stale) skipped via wgt.
// Deterministic: per-wave partials, fixed order.
// ---------------------------------------------------------------------------
__global__ __launch_bounds__(256) void hit_kernel(
    const short* __restrict__ ebf, const float2* __restrict__ up,
    const float2* __restrict__ vcp, const unsigned char* __restrict__ hitb,
    float* __restrict__ negP2) {
    int tid  = threadIdx.x;
    int w    = tid >> 6;
    int lane = tid & 63;
    int lrow = lane & 15, lkh = lane >> 4;
    int gw   = blockIdx.x * 4 + w;     // 128 blocks * 4 waves = 512
    int base = gw * 64;

    float hacc = 0.0f;
    unsigned char myb = hitb[base + lane];
    unsigned long long bal = __ballot(myb != 0);
    while (bal) {
        int l = __builtin_ctzll(bal);
        bal &= bal - 1;
        int idx = base + l;
        unsigned int mask = (unsigned int)__shfl((int)myb, l);
        int strip64 = idx >> 7, tj = idx & 127;
        int rt = strip64 >> 1;
        float wgt = (tj == rt) ? 1.0f : ((tj > rt) ? 2.0f : 0.0f);
        if (wgt == 0.0f) continue;     // stale lower-triangle cell
        int rowbase = strip64 * 64;

        bf16x8 a[4][2];
        float2 ul[4][4];
        #pragma unroll
        for (int s = 0; s < 4; ++s) {
            const short* ab = ebf + (size_t)(rowbase + 16 * s + lrow) * DD + lkh * 8;
            a[s][0] = *(const bf16x8*)(ab);
            a[s][1] = *(const bf16x8*)(ab + 32);
            #pragma unroll
            for (int r = 0; r < 4; ++r)
                ul[s][r] = up[rowbase + 16 * s + lkh * 4 + r];
        }
        float hp = 0.0f;
        for (int t = 0; t < 8; ++t) {
            if (!(mask & (1u << t))) continue;
            const short* bb = ebf + (size_t)(tj * 128 + t * 16 + lrow) * DD + lkh * 8;
            bf16x8 b0 = *(const bf16x8*)(bb);
            bf16x8 b1 = *(const bf16x8*)(bb + 32);
            f32x4 c4[4];
            #pragma unroll
            for (int s = 0; s < 4; ++s) {
                f32x4 z = {0.f, 0.f, 0.f, 0.f};
                z = __builtin_amdgcn_mfma_f32_16x16x32_bf16(a[s][0], b0, z, 0, 0, 0);
                z = __builtin_amdgcn_mfma_f32_16x16x32_bf16(a[s][1], b1, z, 0, 0, 0);
                c4[s] = z;
            }
            float2 vl = vcp[tj * 128 + t * 16 + lrow];
            #pragma unroll
            for (int s = 0; s < 4; ++s) {
                #pragma unroll
                for (int r = 0; r < 4; ++r) {
                    float d2 = fmaf(-2.0f, c4[s][r], ul[s][r].x + vl.x);
                    float d  = sqrtf(fmaxf(d2, 1e-12f));
                    float h  = fmaxf(1.0f - d, 0.0f);
                    if (ul[s][r].y != vl.y) hp = fmaf(h, h, hp);
                }
            }
        }
        hacc = fmaf(wgt, hp, hacc);
    }
    hacc = wave_sum_f(hacc);
    if (lane == 0) negP2[gw] = hacc;   // unconditional: all 512 cells fresh
}

// ---------------------------------------------------------------------------
// Kernel 4: final reduction + 4-replica label histogram -> analytic negative
// count: n_neg = N^2 - sum_c n_c^2 ; n_comparisons = N + n_neg
// ---------------------------------------------------------------------------
__global__ __launch_bounds__(1024) void reduce_kernel(
    const float* __restrict__ posP, const float* __restrict__ negP2,
    const int* __restrict__ lab, float* __restrict__ out) {
    __shared__ unsigned int hist[4][1024];
    int t = threadIdx.x;
    int w = t >> 6, lane = t & 63;
    for (int i = t; i < 4096; i += 1024) hist[i >> 10][i & 1023] = 0u;
    __syncthreads();
    const int4* lab4 = (const int4*)lab;
    for (int i = t; i < NN / 4; i += 1024) {
        int4 v = lab4[i];
        atomicAdd(&hist[w & 3][v.x & 1023], 1u);
        atomicAdd(&hist[w & 3][v.y & 1023], 1u);
        atomicAdd(&hist[w & 3][v.z & 1023], 1u);
        atomicAdd(&hist[w & 3][v.w & 1023], 1u);
    }
    __syncthreads();

    float ps = 0.f, ns = 0.f;
    unsigned long long sqc = 0u;
    const float4* posP4 = (const float4*)posP;
    for (int i = t; i < NPOSB / 4; i += 1024) {
        float4 v = posP4[i];
        ps += (v.x + v.y) + (v.z + v.w);
    }
    if (t < NH2W) ns = negP2[t];
    if (t < 1024) {
        unsigned long long h = (unsigned long long)hist[0][t] + hist[1][t]
                             + hist[2][t] + hist[3][t];
        sqc = h * h;
    }

    ps = wave_sum_f(ps);
    ns = wave_sum_f(ns);
    #pragma unroll
    for (int o = 32; o >= 1; o >>= 1) sqc += __shfl_xor(sqc, o);

    __shared__ float sp[16], sn[16];
    __shared__ unsigned long long sc[16];
    if (lane == 0) { sp[w] = ps; sn[w] = ns; sc[w] = sqc; }
    __syncthreads();
    if (t == 0) {
        float pos = 0.f, neg = 0.f;
        unsigned long long s2 = 0;
        #pragma unroll
        for (int i = 0; i < 16; ++i) { pos += sp[i]; neg += sn[i]; s2 += sc[i]; }
        unsigned long long nneg = (unsigned long long)NN * NN - s2;
        float ncomp = (float)((unsigned long long)NN + nneg);
        out[0] = (pos + neg) / ncomp;
    }
}

// ---------------------------------------------------------------------------
// ws layout (bytes):
//   up    @ 0        : 131072  (float2[16384]: {u, label})
//   vcp   @ 131072   : 131072  (float2[16384]: {vc, label})
//   ebf   @ 262144   : 2097152
//   posP  @ 2359296  : 16384   (NPOSB floats)
//   negP2 @ 2375680  : 2048    (NH2W=512 floats)
//   hitb  @ 2377728  : 32768   (uchar[256*128] hitmasks)
//   total 2410496
// ---------------------------------------------------------------------------
extern "C" void kernel_launch(void* const* d_in, const int* in_sizes, int n_in,
                              void* d_out, int out_size, void* d_ws, size_t ws_size,
                              hipStream_t stream) {
    const float* emb = (const float*)d_in[0];
    const int* lab   = (const int*)d_in[1];
    const int* pidx  = (const int*)d_in[2];
    float* out = (float*)d_out;
    char* ws = (char*)d_ws;
    float2*         up    = (float2*)(ws);
    float2*         vcp   = (float2*)(ws + 131072);
    __hip_bfloat16* ebf   = (__hip_bfloat16*)(ws + 262144);
    float*          posP  = (float*)(ws + 2359296);
    float*          negP2 = (float*)(ws + 2375680);
    unsigned char*  hitb  = (unsigned char*)(ws + 2377728);

    norm_kernel<<<NPOSB, 256, 0, stream>>>(emb, pidx, lab, up, vcp, ebf, posP);
    gram_kernel<<<NBLK, 512, 0, stream>>>((const short*)ebf, hitb);
    hit_kernel<<<128, 256, 0, stream>>>((const short*)ebf, up, vcp, hitb, negP2);
    reduce_kernel<<<1, 1024, 0, stream>>>(posP, negP2, lab, out);
}

// Round 12
// 68.290 us; speedup vs baseline: 1.0135x; 1.0135x over previous
//
#include <hip/hip_runtime.h>
#include <hip/hip_bf16.h>

#define NN 16384
#define DD 64
#define NBI 32                 // 512-row bands
#define NUNITS 2112            // sum_I (128 - 4I), I=0..31
#define NBLK 1024              // 4 blocks/CU (38.9 KB LDS) -> 32 waves/CU
#define NPOSB (NN/4)
#define SCREEN_T 0.49f         // hinge>0 needs gram > ~0.5-3e-5; margin 1e-2

constexpr float F_EPS_PD   = 1e-6f;
constexpr float F_EPS_NORM = 1e-6f;

using bf16x8 = __attribute__((ext_vector_type(8))) short;
using f32x4  = __attribute__((ext_vector_type(4))) float;
typedef __attribute__((address_space(1))) const unsigned int gu32_t;
typedef __attribute__((address_space(3))) unsigned int       lu32_t;

__device__ __forceinline__ float wave_sum_f(float v) {
    #pragma unroll
    for (int o = 32; o >= 1; o >>= 1) v += __shfl_xor(v, o);
    return v;
}

// unit offset of band I (units are (band, col-tile) with tj in [4I,128))
__device__ __forceinline__ int band_off(int I) { return 2 * I * (65 - I); }

// ---------------------------------------------------------------------------
// Kernel 1: per-row normalize + bf16 copy + packed {u,lab}/{vc,lab} + exact
// fp32 positive-pair loss.   d2(i,j) = u_i + vc_j - 2*gram(i,j)
// ---------------------------------------------------------------------------
__global__ __launch_bounds__(256) void norm_kernel(
    const float* __restrict__ emb, const int* __restrict__ pidx,
    const int* __restrict__ lab, float2* __restrict__ up,
    float2* __restrict__ vcp, __hip_bfloat16* __restrict__ ebf,
    float* __restrict__ posP) {
    int w    = threadIdx.x >> 6;
    int row  = blockIdx.x * 4 + w;
    int lane = threadIdx.x & 63;
    int j    = pidx[row];
    float x  = emb[(size_t)row * DD + lane];
    float xj = emb[(size_t)j   * DD + lane];

    float n2  = wave_sum_f(x * x);
    float sx  = wave_sum_f(x);
    float n2j = wave_sum_f(xj * xj);
    float sxj = wave_sum_f(xj);
    float dot = wave_sum_f(x * xj);

    float m  = fmaxf(sqrtf(n2),  F_EPS_NORM);
    float mj = fmaxf(sqrtf(n2j), F_EPS_NORM);
    ebf[(size_t)row * DD + lane] = __float2bfloat16(x / m);

    __shared__ float spos[4];
    if (lane == 0) {
        float sq  = n2 / (m * m);
        float sqj = n2j / (mj * mj);
        float s   = sx / m;
        float sj  = sxj / mj;
        float g   = dot / (m * mj);
        float lf  = (float)lab[row];
        up[row]  = make_float2(sq + 2.0f * F_EPS_PD * s, lf);
        vcp[row] = make_float2(
            sq - 2.0f * F_EPS_PD * s + (float)DD * F_EPS_PD * F_EPS_PD, lf);
        float d2p = sq + sqj - 2.0f * g + 2.0f * F_EPS_PD * (s - sj)
                  + (float)DD * F_EPS_PD * F_EPS_PD;
        spos[w] = fmaxf(d2p, 0.0f);
    }
    __syncthreads();
    if (threadIdx.x == 0)
        posP[blockIdx.x] = spos[0] + spos[1] + spos[2] + spos[3];
}

// ---------------------------------------------------------------------------
// Stage one (B tile 16 KB + vcp slice 1 KB) into a ring slot. 3 ops per wave
// (uniform -> exact vmcnt counts). B source XOR-preswizzled (both-sides rule):
// LDS row r, 16B slot c holds global chunk c^(r&7); matching read-XOR in
// compute. vcp slice staged redundantly by all 8 waves (identical data).
// ---------------------------------------------------------------------------
__device__ __forceinline__ void stage_tile(const short* ebf, const float2* vcp,
                                           int tile, short* slotB, float2* slotV,
                                           int w, int lane) {
    const short* tbase = ebf + (size_t)tile * (128 * DD);
    int rlo = lane >> 3;
    int g   = (lane & 7) ^ rlo;
    #pragma unroll
    for (int q = 0; q < 2; ++q) {
        int m = w * 2 + q;
        __builtin_amdgcn_global_load_lds(
            (gu32_t*)(const void*)(tbase + (size_t)(8 * m + rlo) * DD + g * 8),
            (lu32_t*)(void*)(slotB + m * 512), 16, 0, 0);
    }
    __builtin_amdgcn_global_load_lds(
        (gu32_t*)(const void*)(vcp + (size_t)tile * 128 + lane * 2),
        (lu32_t*)(void*)slotV, 16, 0, 0);
}

// ---------------------------------------------------------------------------
// Kernel 2: 8-wave blocks over (512-row band I, 128-col tile tj), tj>=4I.
// OCCUPANCY-FIRST variant (R12): 2-slot ring (38.9 KB LDS) -> 4 blocks/CU =
// 32 waves/CU; cross-block TLP is the latency-hiding mechanism (m97-style).
// Per iter (one barrier): s_barrier ; stage(k+1) ; vmcnt(3) [last: 0] ;
// compute(k). Write-after-read safe: barrier precedes slot overwrite; vmcnt
// counts exact (prologue A/uband loads are oldest, drained at iter 0).
// Zero vmem in compute (rare path reads uband/ringV LDS only).
// ---------------------------------------------------------------------------
__global__ __launch_bounds__(512, 8) void pair_kernel(
    const short* __restrict__ ebf, const float2* __restrict__ up,
    const float2* __restrict__ vcp, float* __restrict__ negP) {
    __shared__ short  ringB[2][8192];   // 2 x 16 KB B tiles (swizzled)
    __shared__ float2 ringV[2][128];    // 2 x 1 KB {vc,lab} slices
    __shared__ float2 uband[512];       // band {u,lab}, staged per segment
    __shared__ float  sred[8];
    int tid  = threadIdx.x;
    int w    = tid >> 6;
    int lane = tid & 63;
    int lrow = lane & 15, lkh = lane >> 4;
    int c0s  = ((lkh)     ^ (lrow & 7)) * 8;   // swizzled K[0:32) chunk
    int c1s  = ((lkh + 4) ^ (lrow & 7)) * 8;   // swizzled K[32:64) chunk

    int ks = (int)(((long long)blockIdx.x * NUNITS) / NBLK);
    int ke = (int)(((long long)(blockIdx.x + 1) * NUNITS) / NBLK);

    // decode ks -> band I
    int I = (int)((65.0f - sqrtf(4225.0f - 2.0f * (float)ks)) * 0.5f);
    I = I < 0 ? 0 : (I > NBI - 1 ? NBI - 1 : I);
    while (band_off(I) > ks) --I;
    while (I < NBI - 1 && band_off(I + 1) <= ks) ++I;

    float hacc = 0.0f;
    int u0 = ks;
    while (u0 < ke) {
        int bend = band_off(I + 1);
        int n    = (ke < bend ? ke : bend) - u0;
        int tj0  = 4 * I + (u0 - band_off(I));
        int rowbase = I * 512 + w * 64;
        int rt      = 4 * I + (w >> 1);

        // --- segment prologue: A frags, u-band stage, prime slot 0 ---
        bf16x8 a[4][2];
        #pragma unroll
        for (int s = 0; s < 4; ++s) {
            const short* ab = ebf + (size_t)(rowbase + 16 * s + lrow) * DD + lkh * 8;
            a[s][0] = *(const bf16x8*)(ab);
            a[s][1] = *(const bf16x8*)(ab + 32);
        }
        if (w < 4)
            __builtin_amdgcn_global_load_lds(
                (gu32_t*)(const void*)(up + (size_t)I * 512 + w * 128 + lane * 2),
                (lu32_t*)(void*)(uband + w * 128), 16, 0, 0);
        stage_tile(ebf, vcp, tj0, &ringB[0][0], &ringV[0][0], w, lane);

        for (int k = 0; k < n; ++k) {
            // all waves done reading slot[(k+1)&1] (= slot of k-1) -> safe
            __builtin_amdgcn_s_barrier();
            __builtin_amdgcn_sched_barrier(0);
            if (k + 1 < n) {
                stage_tile(ebf, vcp, tj0 + k + 1, &ringB[(k + 1) & 1][0],
                           &ringV[(k + 1) & 1][0], w, lane);
                asm volatile("s_waitcnt vmcnt(3)" ::: "memory");
            } else {
                asm volatile("s_waitcnt vmcnt(0)" ::: "memory");
            }
            __builtin_amdgcn_sched_barrier(0);

            int tj = tj0 + k;
            float wgt = (tj == rt) ? 1.0f : ((tj > rt) ? 2.0f : 0.0f);
            if (wgt != 0.0f) {
                const short*  lb = &ringB[k & 1][0];
                const float2* lv = &ringV[k & 1][0];
                float hp = 0.0f;
                #pragma unroll
                for (int t = 0; t < 8; ++t) {
                    const short* rowp = lb + (t * 16 + lrow) * 64;
                    bf16x8 b0 = *(const bf16x8*)(rowp + c0s);
                    bf16x8 b1 = *(const bf16x8*)(rowp + c1s);
                    __builtin_amdgcn_s_setprio(1);
                    f32x4 c4[4];
                    #pragma unroll
                    for (int s = 0; s < 4; ++s) {
                        f32x4 z = {0.f, 0.f, 0.f, 0.f};
                        z = __builtin_amdgcn_mfma_f32_16x16x32_bf16(a[s][0], b0, z, 0, 0, 0);
                        z = __builtin_amdgcn_mfma_f32_16x16x32_bf16(a[s][1], b1, z, 0, 0, 0);
                        c4[s] = z;
                    }
                    __builtin_amdgcn_s_setprio(0);
                    // 4 independent 3-deep chains + shallow combine
                    float m0 = fmaxf(fmaxf(c4[0][0], c4[0][1]), fmaxf(c4[0][2], c4[0][3]));
                    float m1 = fmaxf(fmaxf(c4[1][0], c4[1][1]), fmaxf(c4[1][2], c4[1][3]));
                    float m2 = fmaxf(fmaxf(c4[2][0], c4[2][1]), fmaxf(c4[2][2], c4[2][3]));
                    float m3 = fmaxf(fmaxf(c4[3][0], c4[3][1]), fmaxf(c4[3][2], c4[3][3]));
                    float mx = fmaxf(fmaxf(m0, m1), fmaxf(m2, m3));
                    if (__any(mx > SCREEN_T)) {            // rare; LDS-only path
                        float2 vl = lv[t * 16 + lrow];
                        #pragma unroll
                        for (int s = 0; s < 4; ++s) {
                            #pragma unroll
                            for (int r = 0; r < 4; ++r) {
                                float2 ul = uband[w * 64 + 16 * s + lkh * 4 + r];
                                float d2 = fmaf(-2.0f, c4[s][r], ul.x + vl.x);
                                float d  = sqrtf(fmaxf(d2, 1e-12f));
                                float h  = fmaxf(1.0f - d, 0.0f);
                                if (ul.y != vl.y) hp = fmaf(h, h, hp);
                            }
                        }
                    }
                }
                hacc = fmaf(wgt, hp, hacc);
            }
        }
        __builtin_amdgcn_s_barrier();      // protect ring/uband reuse
        __builtin_amdgcn_sched_barrier(0);
        u0 += n;
        ++I;
    }

    hacc = wave_sum_f(hacc);
    if (lane == 0) sred[w] = hacc;
    __syncthreads();
    if (tid == 0) {
        float tn = 0.f;
        #pragma unroll
        for (int i = 0; i < 8; ++i) tn += sred[i];
        negP[blockIdx.x] = tn;
    }
}

// ---------------------------------------------------------------------------
// Kernel 3: final reduction + 4-replica label histogram -> analytic negative
// count: n_neg = N^2 - sum_c n_c^2 ; n_comparisons = N + n_neg
// ---------------------------------------------------------------------------
__global__ __launch_bounds__(1024) void reduce_kernel(
    const float* __restrict__ posP, const float* __restrict__ negP,
    const int* __restrict__ lab, float* __restrict__ out) {
    __shared__ unsigned int hist[4][1024];
    int t = threadIdx.x;
    int w = t >> 6, lane = t & 63;
    for (int i = t; i < 4096; i += 1024) hist[i >> 10][i & 1023] = 0u;
    __syncthreads();
    const int4* lab4 = (const int4*)lab;
    for (int i = t; i < NN / 4; i += 1024) {
        int4 v = lab4[i];
        atomicAdd(&hist[w & 3][v.x & 1023], 1u);
        atomicAdd(&hist[w & 3][v.y & 1023], 1u);
        atomicAdd(&hist[w & 3][v.z & 1023], 1u);
        atomicAdd(&hist[w & 3][v.w & 1023], 1u);
    }
    __syncthreads();

    float ps = 0.f, ns = 0.f;
    unsigned long long sqc = 0u;
    const float4* posP4 = (const float4*)posP;
    for (int i = t; i < NPOSB / 4; i += 1024) {
        float4 v = posP4[i];
        ps += (v.x + v.y) + (v.z + v.w);
    }
    ns = negP[t];                      // NBLK == 1024 == blockDim
    {
        unsigned long long h = (unsigned long long)hist[0][t & 1023] + hist[1][t & 1023]
                             + hist[2][t & 1023] + hist[3][t & 1023];
        sqc = h * h;
    }

    ps = wave_sum_f(ps);
    ns = wave_sum_f(ns);
    #pragma unroll
    for (int o = 32; o >= 1; o >>= 1) sqc += __shfl_xor(sqc, o);

    __shared__ float sp[16], sn[16];
    __shared__ unsigned long long sc[16];
    if (lane == 0) { sp[w] = ps; sn[w] = ns; sc[w] = sqc; }
    __syncthreads();
    if (t == 0) {
        float pos = 0.f, neg = 0.f;
        unsigned long long s2 = 0;
        #pragma unroll
        for (int i = 0; i < 16; ++i) { pos += sp[i]; neg += sn[i]; s2 += sc[i]; }
        unsigned long long nneg = (unsigned long long)NN * NN - s2;
        float ncomp = (float)((unsigned long long)NN + nneg);
        out[0] = (pos + neg) / ncomp;
    }
}

// ---------------------------------------------------------------------------
// ws layout (bytes):
//   up   @ 0        : 131072  (float2[16384]: {u, label})
//   vcp  @ 131072   : 131072  (float2[16384]: {vc, label})
//   ebf  @ 262144   : 2097152
//   posP @ 2359296  : 16384   (NPOSB floats)
//   negP @ 2375680  : 4096    (NBLK=1024 floats)
//   total 2379776
// ---------------------------------------------------------------------------
extern "C" void kernel_launch(void* const* d_in, const int* in_sizes, int n_in,
                              void* d_out, int out_size, void* d_ws, size_t ws_size,
                              hipStream_t stream) {
    const float* emb = (const float*)d_in[0];
    const int* lab   = (const int*)d_in[1];
    const int* pidx  = (const int*)d_in[2];
    float* out = (float*)d_out;
    char* ws = (char*)d_ws;
    float2*         up   = (float2*)(ws);
    float2*         vcp  = (float2*)(ws + 131072);
    __hip_bfloat16* ebf  = (__hip_bfloat16*)(ws + 262144);
    float*          posP = (float*)(ws + 2359296);
    float*          negP = (float*)(ws + 2375680);

    norm_kernel<<<NPOSB, 256, 0, stream>>>(emb, pidx, lab, up, vcp, ebf, posP);
    pair_kernel<<<NBLK, 512, 0, stream>>>((const short*)ebf, up, vcp, negP);
    reduce_kernel<<<1, 1024, 0, stream>>>(posP, negP, lab, out);
}

// Round 13
// 59.134 us; speedup vs baseline: 1.1704x; 1.1548x over previous
//
#include <hip/hip_runtime.h>
#include <hip/hip_bf16.h>

#define NN 16384
#define DD 64
#define NBI 32                 // 512-row bands
#define NUNITS 2112            // sum_I (128 - 4I), I=0..31
#define NBLK 1024              // 4 blocks/CU (39.4 KB LDS) -> 32 waves/CU
#define NPOSB (NN/4)
#define SCREEN_T 0.49f         // hinge>0 needs gram > ~0.5-3e-5; margin 1e-2

constexpr float F_EPS_PD   = 1e-6f;
constexpr float F_EPS_NORM = 1e-6f;

using bf16x8 = __attribute__((ext_vector_type(8))) short;
using f32x4  = __attribute__((ext_vector_type(4))) float;
typedef __attribute__((address_space(1))) const unsigned int gu32_t;
typedef __attribute__((address_space(3))) unsigned int       lu32_t;

__device__ __forceinline__ float wave_sum_f(float v) {
    #pragma unroll
    for (int o = 32; o >= 1; o >>= 1) v += __shfl_xor(v, o);
    return v;
}

// unit offset of band I (units are (band, col-tile) with tj in [4I,128))
__device__ __forceinline__ int band_off(int I) { return 2 * I * (65 - I); }

// ---------------------------------------------------------------------------
// Kernel 1: per-row normalize + bf16 copy + packed {u,lab}/{vc,lab} + exact
// fp32 positive-pair loss.   d2(i,j) = u_i + vc_j - 2*gram(i,j)
// ---------------------------------------------------------------------------
__global__ __launch_bounds__(256) void norm_kernel(
    const float* __restrict__ emb, const int* __restrict__ pidx,
    const int* __restrict__ lab, float2* __restrict__ up,
    float2* __restrict__ vcp, __hip_bfloat16* __restrict__ ebf,
    float* __restrict__ posP) {
    int w    = threadIdx.x >> 6;
    int row  = blockIdx.x * 4 + w;
    int lane = threadIdx.x & 63;
    int j    = pidx[row];
    float x  = emb[(size_t)row * DD + lane];
    float xj = emb[(size_t)j   * DD + lane];

    float n2  = wave_sum_f(x * x);
    float sx  = wave_sum_f(x);
    float n2j = wave_sum_f(xj * xj);
    float sxj = wave_sum_f(xj);
    float dot = wave_sum_f(x * xj);

    float m  = fmaxf(sqrtf(n2),  F_EPS_NORM);
    float mj = fmaxf(sqrtf(n2j), F_EPS_NORM);
    ebf[(size_t)row * DD + lane] = __float2bfloat16(x / m);

    __shared__ float spos[4];
    if (lane == 0) {
        float sq  = n2 / (m * m);
        float sqj = n2j / (mj * mj);
        float s   = sx / m;
        float sj  = sxj / mj;
        float g   = dot / (m * mj);
        float lf  = (float)lab[row];
        up[row]  = make_float2(sq + 2.0f * F_EPS_PD * s, lf);
        vcp[row] = make_float2(
            sq - 2.0f * F_EPS_PD * s + (float)DD * F_EPS_PD * F_EPS_PD, lf);
        float d2p = sq + sqj - 2.0f * g + 2.0f * F_EPS_PD * (s - sj)
                  + (float)DD * F_EPS_PD * F_EPS_PD;
        spos[w] = fmaxf(d2p, 0.0f);
    }
    __syncthreads();
    if (threadIdx.x == 0)
        posP[blockIdx.x] = spos[0] + spos[1] + spos[2] + spos[3];
}

// ---------------------------------------------------------------------------
// Stage one (B tile 16 KB + vcp slice 1 KB) into a ring slot. 3 ops per wave
// (uniform -> exact vmcnt counts). B source XOR-preswizzled (both-sides rule):
// LDS row r, 16B slot c holds global chunk c^(r&7); matching read-XOR in
// compute. vcp slice staged redundantly by all 8 waves (identical data).
// ---------------------------------------------------------------------------
__device__ __forceinline__ void stage_tile(const short* ebf, const float2* vcp,
                                           int tile, short* slotB, float2* slotV,
                                           int w, int lane) {
    const short* tbase = ebf + (size_t)tile * (128 * DD);
    int rlo = lane >> 3;
    int g   = (lane & 7) ^ rlo;
    #pragma unroll
    for (int q = 0; q < 2; ++q) {
        int m = w * 2 + q;
        __builtin_amdgcn_global_load_lds(
            (gu32_t*)(const void*)(tbase + (size_t)(8 * m + rlo) * DD + g * 8),
            (lu32_t*)(void*)(slotB + m * 512), 16, 0, 0);
    }
    __builtin_amdgcn_global_load_lds(
        (gu32_t*)(const void*)(vcp + (size_t)tile * 128 + lane * 2),
        (lu32_t*)(void*)slotV, 16, 0, 0);
}

// ---------------------------------------------------------------------------
// Kernel 2: 8-wave blocks over (512-row band I, 128-col tile tj), tj>=4I.
// R13 = R12 structure with the R8-proven register budget: __launch_bounds__
// (512,4) -> compiler picks ~52 VGPR (no spill; R12's (512,8) forced 32 VGPR
// and 100 MB of scratch traffic). 52 <= 64 => HW can run 8 waves/SIMD; LDS
// 39.4 KB => 4 blocks/CU; net 32 waves/CU co-resident, clean codegen.
// Per iter (one barrier): s_barrier ; stage(k+1) ; vmcnt(3) [last: 0] ;
// compute(k). Zero vmem in compute (rare path reads uband/ringV LDS only).
// ---------------------------------------------------------------------------
__global__ __launch_bounds__(512, 4) void pair_kernel(
    const short* __restrict__ ebf, const float2* __restrict__ up,
    const float2* __restrict__ vcp, float* __restrict__ negP) {
    __shared__ short  ringB[2][8192];   // 2 x 16 KB B tiles (swizzled)
    __shared__ float2 ringV[2][128];    // 2 x 1 KB {vc,lab} slices
    __shared__ float2 uband[512];       // band {u,lab}, staged per segment
    __shared__ float  sred[8];
    int tid  = threadIdx.x;
    int w    = tid >> 6;
    int lane = tid & 63;
    int lrow = lane & 15, lkh = lane >> 4;
    int c0s  = ((lkh)     ^ (lrow & 7)) * 8;   // swizzled K[0:32) chunk
    int c1s  = ((lkh + 4) ^ (lrow & 7)) * 8;   // swizzled K[32:64) chunk

    int ks = (int)(((long long)blockIdx.x * NUNITS) / NBLK);
    int ke = (int)(((long long)(blockIdx.x + 1) * NUNITS) / NBLK);

    // decode ks -> band I
    int I = (int)((65.0f - sqrtf(4225.0f - 2.0f * (float)ks)) * 0.5f);
    I = I < 0 ? 0 : (I > NBI - 1 ? NBI - 1 : I);
    while (band_off(I) > ks) --I;
    while (I < NBI - 1 && band_off(I + 1) <= ks) ++I;

    float hacc = 0.0f;
    int u0 = ks;
    while (u0 < ke) {
        int bend = band_off(I + 1);
        int n    = (ke < bend ? ke : bend) - u0;
        int tj0  = 4 * I + (u0 - band_off(I));
        int rowbase = I * 512 + w * 64;
        int rt      = 4 * I + (w >> 1);

        // --- segment prologue: A frags, u-band stage, prime slot 0 ---
        bf16x8 a[4][2];
        #pragma unroll
        for (int s = 0; s < 4; ++s) {
            const short* ab = ebf + (size_t)(rowbase + 16 * s + lrow) * DD + lkh * 8;
            a[s][0] = *(const bf16x8*)(ab);
            a[s][1] = *(const bf16x8*)(ab + 32);
        }
        if (w < 4)
            __builtin_amdgcn_global_load_lds(
                (gu32_t*)(const void*)(up + (size_t)I * 512 + w * 128 + lane * 2),
                (lu32_t*)(void*)(uband + w * 128), 16, 0, 0);
        stage_tile(ebf, vcp, tj0, &ringB[0][0], &ringV[0][0], w, lane);

        for (int k = 0; k < n; ++k) {
            // all waves done reading slot[(k+1)&1] (= slot of k-1) -> safe
            __builtin_amdgcn_s_barrier();
            __builtin_amdgcn_sched_barrier(0);
            if (k + 1 < n) {
                stage_tile(ebf, vcp, tj0 + k + 1, &ringB[(k + 1) & 1][0],
                           &ringV[(k + 1) & 1][0], w, lane);
                asm volatile("s_waitcnt vmcnt(3)" ::: "memory");
            } else {
                asm volatile("s_waitcnt vmcnt(0)" ::: "memory");
            }
            __builtin_amdgcn_sched_barrier(0);

            int tj = tj0 + k;
            float wgt = (tj == rt) ? 1.0f : ((tj > rt) ? 2.0f : 0.0f);
            if (wgt != 0.0f) {
                const short*  lb = &ringB[k & 1][0];
                const float2* lv = &ringV[k & 1][0];
                float hp = 0.0f;
                #pragma unroll
                for (int t = 0; t < 8; ++t) {
                    const short* rowp = lb + (t * 16 + lrow) * 64;
                    bf16x8 b0 = *(const bf16x8*)(rowp + c0s);
                    bf16x8 b1 = *(const bf16x8*)(rowp + c1s);
                    __builtin_amdgcn_s_setprio(1);
                    f32x4 c4[4];
                    #pragma unroll
                    for (int s = 0; s < 4; ++s) {
                        f32x4 z = {0.f, 0.f, 0.f, 0.f};
                        z = __builtin_amdgcn_mfma_f32_16x16x32_bf16(a[s][0], b0, z, 0, 0, 0);
                        z = __builtin_amdgcn_mfma_f32_16x16x32_bf16(a[s][1], b1, z, 0, 0, 0);
                        c4[s] = z;
                    }
                    __builtin_amdgcn_s_setprio(0);
                    float m0 = fmaxf(fmaxf(c4[0][0], c4[0][1]), fmaxf(c4[0][2], c4[0][3]));
                    float m1 = fmaxf(fmaxf(c4[1][0], c4[1][1]), fmaxf(c4[1][2], c4[1][3]));
                    float m2 = fmaxf(fmaxf(c4[2][0], c4[2][1]), fmaxf(c4[2][2], c4[2][3]));
                    float m3 = fmaxf(fmaxf(c4[3][0], c4[3][1]), fmaxf(c4[3][2], c4[3][3]));
                    float mx = fmaxf(fmaxf(m0, m1), fmaxf(m2, m3));
                    if (__any(mx > SCREEN_T)) {            // rare; LDS-only path
                        float2 vl = lv[t * 16 + lrow];
                        #pragma unroll
                        for (int s = 0; s < 4; ++s) {
                            #pragma unroll
                            for (int r = 0; r < 4; ++r) {
                                float2 ul = uband[w * 64 + 16 * s + lkh * 4 + r];
                                float d2 = fmaf(-2.0f, c4[s][r], ul.x + vl.x);
                                float d  = sqrtf(fmaxf(d2, 1e-12f));
                                float h  = fmaxf(1.0f - d, 0.0f);
                                if (ul.y != vl.y) hp = fmaf(h, h, hp);
                            }
                        }
                    }
                }
                hacc = fmaf(wgt, hp, hacc);
            }
        }
        __builtin_amdgcn_s_barrier();      // protect ring/uband reuse
        __builtin_amdgcn_sched_barrier(0);
        u0 += n;
        ++I;
    }

    hacc = wave_sum_f(hacc);
    if (lane == 0) sred[w] = hacc;
    __syncthreads();
    if (tid == 0) {
        float tn = 0.f;
        #pragma unroll
        for (int i = 0; i < 8; ++i) tn += sred[i];
        negP[blockIdx.x] = tn;
    }
}

// ---------------------------------------------------------------------------
// Kernel 3: final reduction + 4-replica label histogram -> analytic negative
// count: n_neg = N^2 - sum_c n_c^2 ; n_comparisons = N + n_neg
// ---------------------------------------------------------------------------
__global__ __launch_bounds__(1024) void reduce_kernel(
    const float* __restrict__ posP, const float* __restrict__ negP,
    const int* __restrict__ lab, float* __restrict__ out) {
    __shared__ unsigned int hist[4][1024];
    int t = threadIdx.x;
    int w = t >> 6, lane = t & 63;
    for (int i = t; i < 4096; i += 1024) hist[i >> 10][i & 1023] = 0u;
    __syncthreads();
    const int4* lab4 = (const int4*)lab;
    for (int i = t; i < NN / 4; i += 1024) {
        int4 v = lab4[i];
        atomicAdd(&hist[w & 3][v.x & 1023], 1u);
        atomicAdd(&hist[w & 3][v.y & 1023], 1u);
        atomicAdd(&hist[w & 3][v.z & 1023], 1u);
        atomicAdd(&hist[w & 3][v.w & 1023], 1u);
    }
    __syncthreads();

    float ps = 0.f, ns = 0.f;
    unsigned long long sqc = 0u;
    const float4* posP4 = (const float4*)posP;
    for (int i = t; i < NPOSB / 4; i += 1024) {
        float4 v = posP4[i];
        ps += (v.x + v.y) + (v.z + v.w);
    }
    ns = negP[t];                      // NBLK == 1024 == blockDim
    {
        unsigned long long h = (unsigned long long)hist[0][t & 1023] + hist[1][t & 1023]
                             + hist[2][t & 1023] + hist[3][t & 1023];
        sqc = h * h;
    }

    ps = wave_sum_f(ps);
    ns = wave_sum_f(ns);
    #pragma unroll
    for (int o = 32; o >= 1; o >>= 1) sqc += __shfl_xor(sqc, o);

    __shared__ float sp[16], sn[16];
    __shared__ unsigned long long sc[16];
    if (lane == 0) { sp[w] = ps; sn[w] = ns; sc[w] = sqc; }
    __syncthreads();
    if (t == 0) {
        float pos = 0.f, neg = 0.f;
        unsigned long long s2 = 0;
        #pragma unroll
        for (int i = 0; i < 16; ++i) { pos += sp[i]; neg += sn[i]; s2 += sc[i]; }
        unsigned long long nneg = (unsigned long long)NN * NN - s2;
        float ncomp = (float)((unsigned long long)NN + nneg);
        out[0] = (pos + neg) / ncomp;
    }
}

// ---------------------------------------------------------------------------
// ws layout (bytes):
//   up   @ 0        : 131072  (float2[16384]: {u, label})
//   vcp  @ 131072   : 131072  (float2[16384]: {vc, label})
//   ebf  @ 262144   : 2097152
//   posP @ 2359296  : 16384   (NPOSB floats)
//   negP @ 2375680  : 4096    (NBLK=1024 floats)
//   total 2379776
// ---------------------------------------------------------------------------
extern "C" void kernel_launch(void* const* d_in, const int* in_sizes, int n_in,
                              void* d_out, int out_size, void* d_ws, size_t ws_size,
                              hipStream_t stream) {
    const float* emb = (const float*)d_in[0];
    const int* lab   = (const int*)d_in[1];
    const int* pidx  = (const int*)d_in[2];
    float* out = (float*)d_out;
    char* ws = (char*)d_ws;
    float2*         up   = (float2*)(ws);
    float2*         vcp  = (float2*)(ws + 131072);
    __hip_bfloat16* ebf  = (__hip_bfloat16*)(ws + 262144);
    float*          posP = (float*)(ws + 2359296);
    float*          negP = (float*)(ws + 2375680);

    norm_kernel<<<NPOSB, 256, 0, stream>>>(emb, pidx, lab, up, vcp, ebf, posP);
    pair_kernel<<<NBLK, 512, 0, stream>>>((const short*)ebf, up, vcp, negP);
    reduce_kernel<<<1, 1024, 0, stream>>>(posP, negP, lab, out);
}